// Round 1
// baseline (924.635 us; speedup 1.0000x reference)
//
#include <hip/hip_runtime.h>
#include <math.h>

// Problem: B=4,H=16,L=1024,D=64. Forward of gumbel_softmax(hard=True) is an
// EXACT one-hot (fp analysis: (1-s)+s rounds to 1, (0-s)+s == 0), so:
//   m*  = argmax_m( 0.125 * dot(elu(q_l), elu(k_m)) + gumbel[l,m] )
//   out = drop_mask[l,m*] * elu(v[m*,:])
// Kernel 1: fp32 tiled GEMM-argmax, tracks top-2 per row (guards fp32 rounding).
// Kernel 2: fp64 re-evaluation of the two candidates -> exact argmax -> output.

#define BH      64
#define SEQ     1024
#define DIM     64
#define LT      128
#define MT      128
#define NTHR    256

__device__ __forceinline__ float eluf(float x) { return x > 0.0f ? x : expm1f(x); }
__device__ __forceinline__ double elud(double x) { return x > 0.0 ? x : expm1(x); }

__device__ __forceinline__ void top2_update(float v, int m,
                                            float& b1, int& i1,
                                            float& b2, int& i2) {
    // prefer larger value; on exact tie prefer smaller index (numpy argmax)
    if (v > b1 || (v == b1 && m < i1)) { b2 = b1; i2 = i1; b1 = v; i1 = m; }
    else if (v > b2 || (v == b2 && m < i2)) { b2 = v; i2 = m; }
}

// ---------------- kernel 1: top-2 argmax over logits ----------------
// grid 512 (= 64 bh * 8 l-tiles), 256 threads.
// LDS tiles are XOR-swizzled on the d-quad index by (row>>3) so both the
// b128 staging writes and the b128 compute reads are bank-conflict free.
__global__ __launch_bounds__(NTHR, 2)
void argmax_top2_kernel(const float* __restrict__ q,
                        const float* __restrict__ k,
                        const float* __restrict__ gum,
                        int* __restrict__ m1out,
                        int* __restrict__ m2out) {
    __shared__ float4 qs4[LT * 16];   // [row][swizzled d-quad], 32 KB
    __shared__ float4 ks4[MT * 16];   // 32 KB

    const int tid = threadIdx.x;
    const int bh  = blockIdx.x >> 3;
    const int l0  = (blockIdx.x & 7) * LT;

    // ---- stage q tile (elu applied), once ----
    const float4* qg = (const float4*)q;
    #pragma unroll
    for (int i = 0; i < (LT * 16) / NTHR; ++i) {
        int f = tid + NTHR * i;
        int row = f >> 4, g = f & 15;
        float4 val = qg[(size_t)(bh * SEQ + l0 + row) * 16 + g];
        val.x = eluf(val.x); val.y = eluf(val.y);
        val.z = eluf(val.z); val.w = eluf(val.w);
        qs4[row * 16 + (g ^ (row >> 3))] = val;
    }

    const int ti = tid >> 4;   // 0..15 -> rows ti*8..ti*8+7
    const int tj = tid & 15;   // 0..15 -> cols tj*8..tj*8+7

    float best1[8], best2[8];
    int   idx1[8], idx2[8];
    #pragma unroll
    for (int i = 0; i < 8; ++i) {
        best1[i] = -INFINITY; best2[i] = -INFINITY; idx1[i] = 0; idx2[i] = 0;
    }

    const float4* kg = (const float4*)k;

    for (int mt = 0; mt < SEQ / MT; ++mt) {
        const int m0 = mt * MT;
        __syncthreads();
        // ---- stage k tile (elu applied) ----
        #pragma unroll
        for (int i = 0; i < (MT * 16) / NTHR; ++i) {
            int f = tid + NTHR * i;
            int row = f >> 4, g = f & 15;
            float4 val = kg[(size_t)(bh * SEQ + m0 + row) * 16 + g];
            val.x = eluf(val.x); val.y = eluf(val.y);
            val.z = eluf(val.z); val.w = eluf(val.w);
            ks4[row * 16 + (g ^ (row >> 3))] = val;
        }
        __syncthreads();

        // ---- 8x8 register-tile fp32 GEMM over d ----
        float acc[8][8];
        #pragma unroll
        for (int i = 0; i < 8; ++i)
            #pragma unroll
            for (int j = 0; j < 8; ++j) acc[i][j] = 0.0f;

        for (int g = 0; g < 16; ++g) {
            float4 a[8];
            #pragma unroll
            for (int i = 0; i < 8; ++i)
                a[i] = qs4[(ti * 8 + i) * 16 + (g ^ ti)];
            #pragma unroll
            for (int jh = 0; jh < 2; ++jh) {
                float4 b[4];
                #pragma unroll
                for (int j = 0; j < 4; ++j)
                    b[j] = ks4[(tj * 8 + jh * 4 + j) * 16 + (g ^ tj)];
                #pragma unroll
                for (int i = 0; i < 8; ++i) {
                    #pragma unroll
                    for (int j = 0; j < 4; ++j) {
                        float t = acc[i][jh * 4 + j];
                        t = fmaf(a[i].x, b[j].x, t);
                        t = fmaf(a[i].y, b[j].y, t);
                        t = fmaf(a[i].z, b[j].z, t);
                        t = fmaf(a[i].w, b[j].w, t);
                        acc[i][jh * 4 + j] = t;
                    }
                }
            }
        }

        // ---- epilogue: + gumbel, top-2 update (ascending m) ----
        #pragma unroll
        for (int i = 0; i < 8; ++i) {
            const int lrow = l0 + ti * 8 + i;
            const float4* gr = (const float4*)(gum + ((size_t)(bh * SEQ + lrow) << 10))
                               + (m0 >> 2) + tj * 2;
            float4 g0 = gr[0], g1 = gr[1];
            float gv[8] = { g0.x, g0.y, g0.z, g0.w, g1.x, g1.y, g1.z, g1.w };
            #pragma unroll
            for (int j = 0; j < 8; ++j) {
                float logit = fmaf(acc[i][j], 0.125f, gv[j]);
                top2_update(logit, m0 + tj * 8 + j,
                            best1[i], idx1[i], best2[i], idx2[i]);
            }
        }
    }

    // ---- reduce top-2 across the 16 tj-lanes sharing each row ----
    #pragma unroll
    for (int i = 0; i < 8; ++i) {
        #pragma unroll
        for (int s = 1; s < 16; s <<= 1) {
            float ob1 = __shfl_xor(best1[i], s, 16);
            int   oi1 = __shfl_xor(idx1[i], s, 16);
            float ob2 = __shfl_xor(best2[i], s, 16);
            int   oi2 = __shfl_xor(idx2[i], s, 16);
            top2_update(ob1, oi1, best1[i], idx1[i], best2[i], idx2[i]);
            top2_update(ob2, oi2, best1[i], idx1[i], best2[i], idx2[i]);
        }
        if (tj == 0) {
            int r = (bh << 10) + l0 + ti * 8 + i;
            m1out[r] = idx1[i];
            m2out[r] = idx2[i];
        }
    }
}

// ---------------- kernel 2: fp64 decide between top-2, emit output ----------------
// one wave per row; 4 rows per 256-thread block; grid 16384.
__global__ __launch_bounds__(NTHR)
void fixup_out_kernel(const float* __restrict__ q,
                      const float* __restrict__ k,
                      const float* __restrict__ v,
                      const float* __restrict__ gum,
                      const float* __restrict__ drop,
                      const int* __restrict__ m1in,
                      const int* __restrict__ m2in,
                      float* __restrict__ out) {
    const int wid  = threadIdx.x >> 6;
    const int lane = threadIdx.x & 63;
    const int r    = blockIdx.x * 4 + wid;       // row id 0..65535
    const int bh   = r >> 10;

    const int m1 = m1in[r], m2 = m2in[r];

    double qe = elud((double)q[(size_t)r * DIM + lane]);
    double k1 = elud((double)k[((size_t)(bh << 10) + m1) * DIM + lane]);
    double k2 = elud((double)k[((size_t)(bh << 10) + m2) * DIM + lane]);
    double s1 = qe * k1;
    double s2 = qe * k2;
    #pragma unroll
    for (int s = 1; s < 64; s <<= 1) {
        s1 += __shfl_xor(s1, s);
        s2 += __shfl_xor(s2, s);
    }
    double L1 = s1 * 0.125 + (double)gum[((size_t)r << 10) + m1];
    double L2 = s2 * 0.125 + (double)gum[((size_t)r << 10) + m2];
    const int mstar = (L2 > L1 || (L2 == L1 && m2 < m1)) ? m2 : m1;

    float dm = drop[((size_t)r << 10) + mstar];
    float fv = v[((size_t)(bh << 10) + mstar) * DIM + lane];
    out[(size_t)r * DIM + lane] = dm * eluf(fv);
}

extern "C" void kernel_launch(void* const* d_in, const int* in_sizes, int n_in,
                              void* d_out, int out_size, void* d_ws, size_t ws_size,
                              hipStream_t stream) {
    const float* q    = (const float*)d_in[0];
    const float* k    = (const float*)d_in[1];
    const float* v    = (const float*)d_in[2];
    const float* gum  = (const float*)d_in[3];
    const float* drop = (const float*)d_in[4];
    float* out = (float*)d_out;

    int* m1 = (int*)d_ws;
    int* m2 = m1 + BH * SEQ;   // 64*1024 rows; 512 KB total workspace

    argmax_top2_kernel<<<dim3(BH * (SEQ / LT)), dim3(NTHR), 0, stream>>>(
        q, k, gum, m1, m2);
    fixup_out_kernel<<<dim3((BH * SEQ) / 4), dim3(NTHR), 0, stream>>>(
        q, k, v, gum, drop, m1, m2, out);
}

// Round 2
// 605.743 us; speedup vs baseline: 1.5264x; 1.5264x over previous
//
#include <hip/hip_runtime.h>
#include <math.h>

// B=4,H=16,L=1024,D=64. gumbel_softmax(hard=True) forward is EXACTLY one-hot:
//   m*  = argmax_m( 0.125 * dot(elu(q_l), elu(k_m)) + gumbel[l,m] )
//   out = drop_mask[l,m*] * elu(v[m*,:])
// Single fused kernel:
//  - scores via bf16 hi/lo split MFMA (3 terms, err ~1.5e-5) -> per-lane top-2
//  - exact fp64-dot fixup of the two candidates (fp32 elu values, exact argmax)
//  - gather v, apply drop, write out.

#define BH    64
#define SEQ   1024
#define DIM   64
#define LT    128      // l-rows per block
#define MT    128      // m-cols per strip
#define NTHR  256

typedef short bf16x8 __attribute__((ext_vector_type(8)));
typedef float f32x16 __attribute__((ext_vector_type(16)));

__device__ __forceinline__ float eluf(float x) { return x > 0.0f ? x : expm1f(x); }

__device__ __forceinline__ unsigned f2bf_bits(float x) {
    unsigned u = __float_as_uint(x);
    return (u + 0x7fffu + ((u >> 16) & 1u)) >> 16;   // RNE
}

__device__ __forceinline__ void top2_update(float v, int m,
                                            float& b1, int& i1,
                                            float& b2, int& i2) {
    bool gt1 = (v > b1) || (v == b1 && m < i1);
    bool gt2 = (v > b2) || (v == b2 && m < i2);
    float nb2 = gt1 ? b1 : (gt2 ? v : b2);
    int   ni2 = gt1 ? i1 : (gt2 ? m : i2);
    b1 = gt1 ? v : b1;
    i1 = gt1 ? m : i1;
    b2 = nb2; i2 = ni2;
}

// stage one 128x64 fp32 tile -> elu -> bf16 hi/lo into swizzled LDS
// LDS layout (shorts): off(row, octet o, j) = row*64 + ((o ^ (row&7))<<3) + j
__device__ __forceinline__ void stage_tile(const float4* __restrict__ src4,
                                           short* __restrict__ hi,
                                           short* __restrict__ lo,
                                           int tid) {
    #pragma unroll
    for (int i = 0; i < 8; ++i) {
        int f = tid + NTHR * i;          // 0..2047
        int row = f >> 4, qd = f & 15;   // qd = d-quad
        float4 val = src4[row * 16 + qd];
        float e0 = eluf(val.x), e1 = eluf(val.y), e2 = eluf(val.z), e3 = eluf(val.w);
        unsigned h0 = f2bf_bits(e0), h1 = f2bf_bits(e1), h2 = f2bf_bits(e2), h3 = f2bf_bits(e3);
        unsigned l0b = f2bf_bits(e0 - __uint_as_float(h0 << 16));
        unsigned l1b = f2bf_bits(e1 - __uint_as_float(h1 << 16));
        unsigned l2b = f2bf_bits(e2 - __uint_as_float(h2 << 16));
        unsigned l3b = f2bf_bits(e3 - __uint_as_float(h3 << 16));
        short4 hv = make_short4((short)h0, (short)h1, (short)h2, (short)h3);
        short4 lv = make_short4((short)l0b, (short)l1b, (short)l2b, (short)l3b);
        int off = row * 64 + ((((qd >> 1) ^ (row & 7)) << 3)) + ((qd & 1) << 2);
        *(short4*)&hi[off] = hv;
        *(short4*)&lo[off] = lv;
    }
}

__global__ __launch_bounds__(NTHR, 2)
void fused_gumbel_attn(const float* __restrict__ q,
                       const float* __restrict__ k,
                       const float* __restrict__ v,
                       const float* __restrict__ gum,
                       const float* __restrict__ drop,
                       float* __restrict__ out) {
    __shared__ __align__(16) short qhi[LT * DIM];
    __shared__ __align__(16) short qlo[LT * DIM];
    __shared__ __align__(16) short khi[MT * DIM];
    __shared__ __align__(16) short klo[MT * DIM];
    __shared__ int   m1s[LT], m2s[LT], msf[LT];
    __shared__ float dropv[LT];

    const int tid  = threadIdx.x;
    const int w    = tid >> 6;          // wave 0..3 -> rows w*32..w*32+31
    const int lane = tid & 63;
    const int lrow = lane & 31;
    const int half = lane >> 5;
    const int bh   = blockIdx.x >> 3;
    const int l0   = (blockIdx.x & 7) * LT;
    const size_t rowbase = (size_t)(bh * SEQ + l0);

    // ---- stage q tile once ----
    stage_tile((const float4*)q + rowbase * 16, qhi, qlo, tid);

    // per-lane persistent top-2: slot r covers row (r&3)+8*(r>>2)+4*half of this wave
    float best1[16], best2[16];
    int   idx1[16], idx2[16];
    #pragma unroll
    for (int r = 0; r < 16; ++r) {
        best1[r] = -INFINITY; best2[r] = -INFINITY; idx1[r] = 0; idx2[r] = 0;
    }

    // per-lane gumbel row base: row = l0 + w*32 + 4*half (+ rowpat offset), col = lane&31
    const float* gumrow = gum + (((size_t)(bh * SEQ + l0 + w * 32 + half * 4)) << 10) + lrow;

    const int aswz = lrow & 7;          // xor-swizzle key for both A and B reads

    for (int mt = 0; mt < SEQ / MT; ++mt) {
        const int m0 = mt * MT;
        __syncthreads();
        stage_tile((const float4*)k + (size_t)(bh * SEQ + m0) * 16, khi, klo, tid);
        __syncthreads();

        // gumbel prefetch for col-tiles 0,1 (issued before MFMA loop)
        float ga[16], gb[16];
        #pragma unroll
        for (int r = 0; r < 16; ++r) {
            int roff = ((r & 3) + 8 * (r >> 2)) << 10;
            ga[r] = gumrow[roff + m0];
            gb[r] = gumrow[roff + m0 + 32];
        }

        f32x16 acc[4];
        #pragma unroll
        for (int t = 0; t < 4; ++t) acc[t] = (f32x16)0.0f;

        #pragma unroll
        for (int ks = 0; ks < 4; ++ks) {
            const int o = ks * 2 + half;             // k-octet index 0..7
            const int arow = w * 32 + lrow;
            bf16x8 a_hi = *(const bf16x8*)&qhi[arow * 64 + ((o ^ aswz) << 3)];
            bf16x8 a_lo = *(const bf16x8*)&qlo[arow * 64 + ((o ^ aswz) << 3)];
            #pragma unroll
            for (int t = 0; t < 4; ++t) {
                const int brow = t * 32 + lrow;
                bf16x8 b_hi = *(const bf16x8*)&khi[brow * 64 + ((o ^ aswz) << 3)];
                bf16x8 b_lo = *(const bf16x8*)&klo[brow * 64 + ((o ^ aswz) << 3)];
                acc[t] = __builtin_amdgcn_mfma_f32_32x32x16_bf16(a_hi, b_hi, acc[t], 0, 0, 0);
                acc[t] = __builtin_amdgcn_mfma_f32_32x32x16_bf16(a_hi, b_lo, acc[t], 0, 0, 0);
                acc[t] = __builtin_amdgcn_mfma_f32_32x32x16_bf16(a_lo, b_hi, acc[t], 0, 0, 0);
            }
        }

        // epilogue: +gumbel, top-2 update. pipeline: consume t0/t1, prefetch t2/t3
        #pragma unroll
        for (int r = 0; r < 16; ++r) {
            float lg = fmaf(acc[0][r], 0.125f, ga[r]);
            top2_update(lg, m0 + lrow, best1[r], idx1[r], best2[r], idx2[r]);
        }
        #pragma unroll
        for (int r = 0; r < 16; ++r) {
            int roff = ((r & 3) + 8 * (r >> 2)) << 10;
            ga[r] = gumrow[roff + m0 + 64];
        }
        #pragma unroll
        for (int r = 0; r < 16; ++r) {
            float lg = fmaf(acc[1][r], 0.125f, gb[r]);
            top2_update(lg, m0 + 32 + lrow, best1[r], idx1[r], best2[r], idx2[r]);
        }
        #pragma unroll
        for (int r = 0; r < 16; ++r) {
            int roff = ((r & 3) + 8 * (r >> 2)) << 10;
            gb[r] = gumrow[roff + m0 + 96];
        }
        #pragma unroll
        for (int r = 0; r < 16; ++r) {
            float lg = fmaf(acc[2][r], 0.125f, ga[r]);
            top2_update(lg, m0 + 64 + lrow, best1[r], idx1[r], best2[r], idx2[r]);
        }
        #pragma unroll
        for (int r = 0; r < 16; ++r) {
            float lg = fmaf(acc[3][r], 0.125f, gb[r]);
            top2_update(lg, m0 + 96 + lrow, best1[r], idx1[r], best2[r], idx2[r]);
        }
    }

    // ---- merge top-2 across the 32 lanes of each half (same rows) ----
    #pragma unroll
    for (int r = 0; r < 16; ++r) {
        #pragma unroll
        for (int s = 1; s < 32; s <<= 1) {
            float ob1 = __shfl_xor(best1[r], s);
            int   oi1 = __shfl_xor(idx1[r], s);
            float ob2 = __shfl_xor(best2[r], s);
            int   oi2 = __shfl_xor(idx2[r], s);
            top2_update(ob1, oi1, best1[r], idx1[r], best2[r], idx2[r]);
            top2_update(ob2, oi2, best1[r], idx1[r], best2[r], idx2[r]);
        }
    }
    if (lrow == 0) {
        #pragma unroll
        for (int r = 0; r < 16; ++r) {
            int local_row = w * 32 + (r & 3) + 8 * (r >> 2) + 4 * half;
            m1s[local_row] = idx1[r];
            m2s[local_row] = idx2[r];
        }
    }
    __syncthreads();

    // ---- fp64 fixup: thread t -> (row = t>>1, cand = t&1), exact dot of fp32 elu ----
    {
        const int row  = tid >> 1;
        const int cand = tid & 1;
        const int m    = cand ? m2s[row] : m1s[row];
        const float4* q4r = (const float4*)q + (rowbase + row) * 16;
        const float4* k4r = (const float4*)k + (size_t)(bh * SEQ + m) * 16;
        double s = 0.0;
        #pragma unroll
        for (int i = 0; i < 16; ++i) {
            float4 a = q4r[i], b = k4r[i];
            s += (double)eluf(a.x) * (double)eluf(b.x);
            s += (double)eluf(a.y) * (double)eluf(b.y);
            s += (double)eluf(a.z) * (double)eluf(b.z);
            s += (double)eluf(a.w) * (double)eluf(b.w);
        }
        double L = s * 0.125 + (double)gum[((rowbase + row) << 10) + m];
        double Lo = __shfl_xor(L, 1);
        int    mo = __shfl_xor(m, 1);
        int mstar = (L > Lo || (L == Lo && m < mo)) ? m : mo;
        if (cand == 0) {
            msf[row]   = mstar;
            dropv[row] = drop[((rowbase + row) << 10) + mstar];
        }
    }
    __syncthreads();

    // ---- output: out[row] = dropv[row] * elu(v[mstar]) ----
    const float4* v4  = (const float4*)v + (size_t)(bh * SEQ) * 16;
    float4*       o4  = (float4*)out + rowbase * 16;
    #pragma unroll
    for (int i = 0; i < 8; ++i) {
        int f = tid + NTHR * i;          // 0..2047
        int row = f >> 4, qd = f & 15;
        int m = msf[row];
        float dm = dropv[row];
        float4 vv = v4[m * 16 + qd];
        float4 ov;
        ov.x = dm * eluf(vv.x); ov.y = dm * eluf(vv.y);
        ov.z = dm * eluf(vv.z); ov.w = dm * eluf(vv.w);
        o4[row * 16 + qd] = ov;
    }
}

extern "C" void kernel_launch(void* const* d_in, const int* in_sizes, int n_in,
                              void* d_out, int out_size, void* d_ws, size_t ws_size,
                              hipStream_t stream) {
    const float* q    = (const float*)d_in[0];
    const float* k    = (const float*)d_in[1];
    const float* v    = (const float*)d_in[2];
    const float* gum  = (const float*)d_in[3];
    const float* drop = (const float*)d_in[4];
    float* out = (float*)d_out;

    fused_gumbel_attn<<<dim3(BH * (SEQ / LT)), dim3(NTHR), 0, stream>>>(
        q, k, v, gum, drop, out);
}

// Round 3
// 574.561 us; speedup vs baseline: 1.6093x; 1.0543x over previous
//
#include <hip/hip_runtime.h>
#include <math.h>

// B=4,H=16,L=1024,D=64. gumbel_softmax(hard=True) forward is EXACTLY one-hot:
//   m*  = argmax_m( 0.125 * dot(elu(q_l), elu(k_m)) + gumbel[l,m] )
//   out = drop_mask[l,m*] * elu(v[m*,:])
// 3 kernels:
//  1. prep: k -> elu -> bf16 hi/lo split into d_ws (16 MB)
//  2. score: barrier-free, LDS-free MFMA (A=k, B=q -> C row=m, col=l).
//     Per-lane single top-2 over its own l-column; 4-way m-split; partials to ws.
//  3. fixup: merge partials, fp64-exact argmax of 2 cands, gather v, write out.

#define BH      64
#define SEQ     1024
#define DIM     64
#define NSPLIT  4
#define MR      (SEQ / NSPLIT)    // 256 m per wave
#define NTILES  (MR / 32)         // 8
#define NTHR    256

typedef short bf16x8 __attribute__((ext_vector_type(8)));
typedef float f32x16 __attribute__((ext_vector_type(16)));

__device__ __forceinline__ float eluf(float x) { return x > 0.0f ? x : expm1f(x); }

__device__ __forceinline__ unsigned f2bf_bits(float x) {
    unsigned u = __float_as_uint(x);
    return (u + 0x7fffu + ((u >> 16) & 1u)) >> 16;   // RNE
}

__device__ __forceinline__ void split_bf16(float x, short& h, short& l) {
    unsigned hb = f2bf_bits(x);
    float hf = __uint_as_float(hb << 16);
    h = (short)hb;
    l = (short)f2bf_bits(x - hf);   // x - hf exact in fp32
}

// strict-> update keeps earliest (smallest m) on exact tie given ascending scan
__device__ __forceinline__ void top2_update(float v, int m,
                                            float& b1, int& i1,
                                            float& b2, int& i2) {
    bool gt1 = v > b1;
    bool gt2 = v > b2;
    float nb2 = gt1 ? b1 : (gt2 ? v : b2);
    int   ni2 = gt1 ? i1 : (gt2 ? m : i2);
    b1 = gt1 ? v : b1;
    i1 = gt1 ? m : i1;
    b2 = nb2; i2 = ni2;
}

// ---------------- kernel 1: k -> elu -> bf16 hi/lo ----------------
__global__ __launch_bounds__(NTHR)
void prep_k_kernel(const float4* __restrict__ k4,
                   short4* __restrict__ khi, short4* __restrict__ klo) {
    int f = blockIdx.x * NTHR + threadIdx.x;       // 1,048,576 float4s
    float4 val = k4[f];
    short4 hv, lv;
    split_bf16(eluf(val.x), hv.x, lv.x);
    split_bf16(eluf(val.y), hv.y, lv.y);
    split_bf16(eluf(val.z), hv.z, lv.z);
    split_bf16(eluf(val.w), hv.w, lv.w);
    khi[f] = hv;
    klo[f] = lv;
}

// ---------------- kernel 2: barrier-free score + top-2 ----------------
// wave = (bh, l-tile of 32, m-split of 256). 2048 blocks x 4 waves.
// XCD swizzle: xcd = blockIdx&7 -> bh in [xcd*8, xcd*8+8): 2MB k-slice per L2.
__global__ __launch_bounds__(NTHR, 3)
void score_top2_kernel(const float* __restrict__ q,
                       const short* __restrict__ khi,
                       const short* __restrict__ klo,
                       const float* __restrict__ gum,
                       int4* __restrict__ top2out) {
    const int w    = threadIdx.x >> 6;
    const int lane = threadIdx.x & 63;
    const int lrow = lane & 31;
    const int half = lane >> 5;

    const int x     = blockIdx.x & 7;
    const int j     = blockIdx.x >> 3;     // 0..255
    const int bh    = x * 8 + (j & 7);
    const int ltile = j >> 3;              // 0..31
    const int l0    = ltile * 32;
    const int ms    = w * MR;

    const size_t row = (size_t)bh * SEQ + l0 + lrow;   // this lane's l-row

    // ---- q B-frags in registers (col=lane&31 -> l, d-octet = half) ----
    bf16x8 qh[4], ql[4];
    {
        const float4* q4 = (const float4*)q + row * 16;
        #pragma unroll
        for (int ks = 0; ks < 4; ++ks) {
            float4 a = q4[ks * 4 + half * 2];
            float4 b = q4[ks * 4 + half * 2 + 1];
            float e[8] = { eluf(a.x), eluf(a.y), eluf(a.z), eluf(a.w),
                           eluf(b.x), eluf(b.y), eluf(b.z), eluf(b.w) };
            #pragma unroll
            for (int t = 0; t < 8; ++t) {
                short h, l;
                split_bf16(e[t], h, l);
                qh[ks][t] = h;
                ql[ks][t] = l;
            }
        }
    }

    const short* kh_base = khi + ((size_t)(bh * SEQ + ms + lrow) * 64 + half * 8);
    const short* kl_base = klo + ((size_t)(bh * SEQ + ms + lrow) * 64 + half * 8);
    const float* gp      = gum + (row << 10) + ms + half * 4;

    float b1 = -INFINITY, b2 = -INFINITY;
    int   i1 = 0, i2 = 0;

    bf16x8 ah[2][4], al[2][4];
    float  g[2][16];

    // preload tile 0
    #pragma unroll
    for (int ks = 0; ks < 4; ++ks) {
        ah[0][ks] = *(const bf16x8*)(kh_base + ks * 16);
        al[0][ks] = *(const bf16x8*)(kl_base + ks * 16);
    }
    #pragma unroll
    for (int qd = 0; qd < 4; ++qd) {
        float4 t4 = *(const float4*)(gp + qd * 8);
        g[0][qd * 4 + 0] = t4.x; g[0][qd * 4 + 1] = t4.y;
        g[0][qd * 4 + 2] = t4.z; g[0][qd * 4 + 3] = t4.w;
    }

    #pragma unroll
    for (int t = 0; t < NTILES; ++t) {
        const int cur = t & 1, nxt = cur ^ 1;
        if (t < NTILES - 1) {
            #pragma unroll
            for (int ks = 0; ks < 4; ++ks) {
                ah[nxt][ks] = *(const bf16x8*)(kh_base + (t + 1) * 2048 + ks * 16);
                al[nxt][ks] = *(const bf16x8*)(kl_base + (t + 1) * 2048 + ks * 16);
            }
            #pragma unroll
            for (int qd = 0; qd < 4; ++qd) {
                float4 t4 = *(const float4*)(gp + (t + 1) * 32 + qd * 8);
                g[nxt][qd * 4 + 0] = t4.x; g[nxt][qd * 4 + 1] = t4.y;
                g[nxt][qd * 4 + 2] = t4.z; g[nxt][qd * 4 + 3] = t4.w;
            }
        }

        f32x16 acc = (f32x16)0.0f;
        #pragma unroll
        for (int ks = 0; ks < 4; ++ks) {
            acc = __builtin_amdgcn_mfma_f32_32x32x16_bf16(ah[cur][ks], qh[ks], acc, 0, 0, 0);
            acc = __builtin_amdgcn_mfma_f32_32x32x16_bf16(ah[cur][ks], ql[ks], acc, 0, 0, 0);
            acc = __builtin_amdgcn_mfma_f32_32x32x16_bf16(al[cur][ks], qh[ks], acc, 0, 0, 0);
        }

        // C mapping: m = ms + t*32 + 4*half + (r&3) + 8*(r>>2), l = lane&31
        const int mb = ms + t * 32 + half * 4;
        #pragma unroll
        for (int r = 0; r < 16; ++r) {
            float lg = fmaf(acc[r], 0.125f, g[cur][r]);
            top2_update(lg, mb + (r & 3) + 8 * (r >> 2), b1, i1, b2, i2);
        }
    }

    // merge half-pair (lanes p, p+32 share the same l-column)
    {
        float ob1 = __shfl_xor(b1, 32);
        int   oi1 = __shfl_xor(i1, 32);
        float ob2 = __shfl_xor(b2, 32);
        int   oi2 = __shfl_xor(i2, 32);
        top2_update(ob1, oi1, b1, i1, b2, i2);
        top2_update(ob2, oi2, b1, i1, b2, i2);
    }
    if (half == 0) {
        top2out[row * NSPLIT + w] = make_int4(__float_as_int(b1), i1,
                                              __float_as_int(b2), i2);
    }
}

// ---------------- kernel 3: merge partials, fp64 fixup, emit out ----------------
// 512 blocks x 256 thr; 128 rows/block (all same bh), 2 threads/row (cands).
__global__ __launch_bounds__(NTHR)
void fixup_out_kernel(const float* __restrict__ q,
                      const float* __restrict__ k,
                      const float* __restrict__ v,
                      const float* __restrict__ gum,
                      const float* __restrict__ drop,
                      const int4* __restrict__ top2in,
                      float* __restrict__ out) {
    __shared__ int   msf[128];
    __shared__ float dropv[128];

    const int rloc = threadIdx.x >> 1;
    const int cand = threadIdx.x & 1;
    const size_t row = (size_t)blockIdx.x * 128 + rloc;
    const int bh = (int)(row >> 10);

    float b1 = -INFINITY, b2 = -INFINITY;
    int   i1 = 0, i2 = 0;
    #pragma unroll
    for (int s = 0; s < NSPLIT; ++s) {
        int4 p = top2in[row * NSPLIT + s];
        top2_update(__int_as_float(p.x), p.y, b1, i1, b2, i2);
        top2_update(__int_as_float(p.z), p.w, b1, i1, b2, i2);
    }
    const int m = cand ? i2 : i1;

    const float4* q4r = (const float4*)q + row * 16;
    const float4* k4r = (const float4*)k + ((size_t)bh * SEQ + m) * 16;
    double s = 0.0;
    #pragma unroll
    for (int i = 0; i < 16; ++i) {
        float4 a = q4r[i], b = k4r[i];
        s += (double)eluf(a.x) * (double)eluf(b.x);
        s += (double)eluf(a.y) * (double)eluf(b.y);
        s += (double)eluf(a.z) * (double)eluf(b.z);
        s += (double)eluf(a.w) * (double)eluf(b.w);
    }
    double L  = s * 0.125 + (double)gum[(row << 10) + m];
    double Lo = __shfl_xor(L, 1);
    int    mo = __shfl_xor(m, 1);
    const int mstar = (L > Lo || (L == Lo && m < mo)) ? m : mo;
    if (cand == 0) {
        msf[rloc]   = mstar;
        dropv[rloc] = drop[(row << 10) + mstar];
    }
    __syncthreads();

    const int bh0 = (int)(((size_t)blockIdx.x * 128) >> 10);
    const float4* v4 = (const float4*)v + (size_t)bh0 * SEQ * 16;
    float4* o4 = (float4*)out + (size_t)blockIdx.x * 128 * 16;
    #pragma unroll
    for (int i = 0; i < 8; ++i) {
        int f  = threadIdx.x + NTHR * i;   // 0..2047 = 128 rows x 16 quads
        int rr = f >> 4, qd = f & 15;
        int   mm = msf[rr];
        float dm = dropv[rr];
        float4 vv = v4[mm * 16 + qd];
        float4 ov;
        ov.x = dm * eluf(vv.x); ov.y = dm * eluf(vv.y);
        ov.z = dm * eluf(vv.z); ov.w = dm * eluf(vv.w);
        o4[rr * 16 + qd] = ov;
    }
}

extern "C" void kernel_launch(void* const* d_in, const int* in_sizes, int n_in,
                              void* d_out, int out_size, void* d_ws, size_t ws_size,
                              hipStream_t stream) {
    const float* q    = (const float*)d_in[0];
    const float* k    = (const float*)d_in[1];
    const float* v    = (const float*)d_in[2];
    const float* gum  = (const float*)d_in[3];
    const float* drop = (const float*)d_in[4];
    float* out = (float*)d_out;

    // ws: khi (8 MB) | klo (8 MB) | top2 partials (4 MB)  = 20 MB
    short* khi = (short*)d_ws;
    short* klo = khi + (size_t)BH * SEQ * DIM;
    int4*  top2 = (int4*)((char*)d_ws + (size_t)2 * BH * SEQ * DIM * sizeof(short));

    prep_k_kernel<<<dim3((BH * SEQ * DIM / 4) / NTHR), dim3(NTHR), 0, stream>>>(
        (const float4*)k, (short4*)khi, (short4*)klo);
    score_top2_kernel<<<dim3(BH * (SEQ / 32) * NSPLIT / 4), dim3(NTHR), 0, stream>>>(
        q, khi, klo, gum, top2);
    fixup_out_kernel<<<dim3((BH * SEQ) / 128), dim3(NTHR), 0, stream>>>(
        q, k, v, gum, drop, top2, out);
}